// Round 14
// baseline (237.755 us; speedup 1.0000x reference)
//
#include <hip/hip_runtime.h>
#include <hip/hip_bf16.h>
#include <math.h>

typedef __bf16 bf16x8 __attribute__((ext_vector_type(8)));
typedef __bf16 bf16x2 __attribute__((ext_vector_type(2)));
typedef float f32x4 __attribute__((ext_vector_type(4)));
typedef float f32x16 __attribute__((ext_vector_type(16)));
typedef unsigned u32x2v __attribute__((ext_vector_type(2)));
typedef unsigned u32x4v __attribute__((ext_vector_type(4)));
typedef unsigned short u16;

#define QSCALE 0.04508422002778011f

__device__ __forceinline__ u16 f2b(float f) {
  union { float f; unsigned u; } x; x.f = f;
  unsigned r = x.u + 0x7fffu + ((x.u >> 16) & 1u);   // RNE to bf16
  return (u16)(r >> 16);
}

__device__ __forceinline__ unsigned pkbf(float a, float b) {
  bf16x2 t = { (__bf16)a, (__bf16)b };
  return __builtin_bit_cast(unsigned, t);
}

#define GLOAD_LDS16(g, s)                                                      \
  __builtin_amdgcn_global_load_lds(                                            \
      (__attribute__((address_space(1))) void*)(void*)(g),                     \
      (__attribute__((address_space(3))) void*)(s), 16, 0, 0)

// ---------------- all casts in one dispatch ----------------
// blockIdx.y: 0 = hidden (scale 1), 1..4 = wq(QSCALE), wk, wv, wo
__global__ void cast_all_kernel(const float* __restrict__ hs,
                                const float* __restrict__ wq, const float* __restrict__ wk,
                                const float* __restrict__ wv, const float* __restrict__ wo,
                                u16* __restrict__ hsb, u16* __restrict__ wqkv,
                                u16* __restrict__ wob) {
  const int w = blockIdx.y;
  const float* src; u16* dst; int n4; float scale = 1.0f;
  if (w == 0)      { src = hs; dst = hsb;                 n4 = 8192 * 1024 / 4; }
  else if (w == 1) { src = wq; dst = wqkv;                n4 = 1024 * 1024 / 4; scale = QSCALE; }
  else if (w == 2) { src = wk; dst = wqkv + 1024 * 1024;  n4 = 1024 * 1024 / 4; }
  else if (w == 3) { src = wv; dst = wqkv + 2 * 1024 * 1024; n4 = 1024 * 1024 / 4; }
  else             { src = wo; dst = wob;                 n4 = 1024 * 1024 / 4; }
  int i = blockIdx.x * blockDim.x + threadIdx.x;
  int stride = gridDim.x * blockDim.x;
  for (; i < n4; i += stride) {
    float4 v = ((const float4*)src)[i];
    ushort4 o;
    o.x = f2b(v.x * scale); o.y = f2b(v.y * scale);
    o.z = f2b(v.z * scale); o.w = f2b(v.w * scale);
    ((ushort4*)dst)[i] = o;
  }
}

// ------- 128x128 GEMM, BK=64 (R13-proven) + XCD-chunked 1D swizzle ---------
// OUT_MODE 1: QKV region epilogue ; OUT_MODE 0: fp32 out.
template <int OUT_MODE>
__global__ __launch_bounds__(256) void gemm_nt64(const u16* __restrict__ A,
                                                 const u16* __restrict__ B,
                                                 void* __restrict__ O0,
                                                 u16* __restrict__ Ko,
                                                 u16* __restrict__ Vt,
                                                 int nbx) {
  __shared__ u16 As[128 * 64];
  __shared__ u16 Bs[128 * 64];
  const int tid = threadIdx.x;
  const int wid = tid >> 6, lane = tid & 63;
  const int fr = lane & 15, fg = lane >> 4;
  const int wr = wid >> 1, wc = wid & 1;
  // XCD-chunked swizzle: each XCD owns a contiguous by-range (A-panel reuse)
  const int id = blockIdx.x;
  const int cpx = gridDim.x >> 3;
  const int swzid = (id & 7) * cpx + (id >> 3);
  const int by = swzid / nbx, bx = swzid % nbx;
  const int m0 = by * 128, n0 = bx * 128;
  const int K = 1024;

  f32x4 acc[4][4] = {};

  for (int kt = 0; kt < K; kt += 64) {
#pragma unroll
    for (int i2 = 0; i2 < 4; ++i2) {
      int c = i2 * 256 + tid;
      int row = c >> 3, sl = c & 7;
      int kc = sl ^ (row & 7);                 // pre-swizzled source column
      GLOAD_LDS16(A + (size_t)(m0 + row) * K + kt + kc * 8, (char*)As + c * 16);
      GLOAD_LDS16(B + (size_t)(n0 + row) * K + kt + kc * 8, (char*)Bs + c * 16);
    }
    __syncthreads();

    bf16x8 af[4][2], bfr[4][2];
#pragma unroll
    for (int m = 0; m < 4; ++m) {
      const int row = wr * 64 + m * 16 + fr;
#pragma unroll
      for (int ks = 0; ks < 2; ++ks)
        af[m][ks] = *(const bf16x8*)((const char*)As + row * 128 +
                                     ((ks * 64 + fg * 16) ^ ((fr & 7) << 4)));
    }
#pragma unroll
    for (int n = 0; n < 4; ++n) {
      const int row = wc * 64 + n * 16 + fr;
#pragma unroll
      for (int ks = 0; ks < 2; ++ks)
        bfr[n][ks] = *(const bf16x8*)((const char*)Bs + row * 128 +
                                      ((ks * 64 + fg * 16) ^ ((fr & 7) << 4)));
    }
    __builtin_amdgcn_s_setprio(1);
#pragma unroll
    for (int m = 0; m < 4; ++m)
#pragma unroll
      for (int n = 0; n < 4; ++n)
#pragma unroll
        for (int ks = 0; ks < 2; ++ks)
          acc[m][n] = __builtin_amdgcn_mfma_f32_16x16x32_bf16(af[m][ks], bfr[n][ks],
                                                              acc[m][n], 0, 0, 0);
    __builtin_amdgcn_s_setprio(0);
    __syncthreads();
  }

#pragma unroll
  for (int m = 0; m < 4; ++m)
#pragma unroll
    for (int n = 0; n < 4; ++n) {
      int gr = m0 + wr * 64 + m * 16 + fg * 4;
      int gc = n0 + wc * 64 + n * 16 + fr;
      if (OUT_MODE == 0) {
#pragma unroll
        for (int j = 0; j < 4; ++j)
          ((float*)O0)[(size_t)(gr + j) * 1024 + gc] = acc[m][n][j];
      } else {
        const int region = n0 >> 10;   // 0=Q 1=K 2=V (block-uniform)
        if (region == 2) {
          int vc = gc - 2048;
          int hh = vc >> 6, dd = vc & 63, bb2 = gr >> 11, s0 = gr & 2047;
          ushort4 o;
          o.x = f2b(acc[m][n][0]); o.y = f2b(acc[m][n][1]);
          o.z = f2b(acc[m][n][2]); o.w = f2b(acc[m][n][3]);
          *(ushort4*)(Vt + (((size_t)bb2 * 16 + hh) * 64 + dd) * 2048 + s0) = o;
        } else {
          u16* dst = (region == 0) ? (u16*)O0 : Ko;
          int cc = gc & 1023;
#pragma unroll
          for (int j = 0; j < 4; ++j)
            dst[(size_t)(gr + j) * 1024 + cc] = f2b(acc[m][n][j]);
        }
      }
    }
}

// ------ fused flash attention: K in LDS (R4 path), V DIRECT from global -----
// V-tile (16 KB) is L1-resident and shared by all waves on the CU; its load
// latency hides under the QK+exp2+pack window (~600 cyc). Barrier protects
// only the K staging. Math identical to R4 (V values = R11-verified mapping).
__global__ __launch_bounds__(256, 2) void attn_fwd(const u16* __restrict__ Q,
                                                   const u16* __restrict__ Kg,
                                                   const u16* __restrict__ Vtg,
                                                   u16* __restrict__ O) {
  __shared__ u16 Ks[2][64 * 64];
  const int tid = threadIdx.x;
  const int wid = tid >> 6, lane = tid & 63;
  const int lq = lane & 31, hi = lane >> 5;
  const int id = blockIdx.x;
  const int swz = (id & 7) * 64 + (id >> 3);
  const int qb = swz & 7, bh = swz >> 3;
  const int b = bh >> 4, h = bh & 15;
  const size_t tokBase = (size_t)b * 2048 * 1024 + h * 64;
  const size_t vBase = (size_t)bh * 64 * 2048;
  const int q0 = qb * 256 + wid * 64;

  bf16x8 qfA[4], qfB[4];
#pragma unroll
  for (int s = 0; s < 4; ++s) {
    qfA[s] = *(const bf16x8*)(Q + tokBase + (size_t)(q0 + lq) * 1024 + s * 16 + hi * 8);
    qfB[s] = *(const bf16x8*)(Q + tokBase + (size_t)(q0 + 32 + lq) * 1024 + s * 16 + hi * 8);
  }

  // V per-lane fragment pointers (R11-verified mapping)
  const u16* Vp0 = Vtg + vBase + (size_t)lq * 2048 + hi * 8;         // d row lq
  const u16* Vp1 = Vtg + vBase + (size_t)(32 + lq) * 2048 + hi * 8;  // d row 32+lq

  f32x16 accA0 = {}, accA1 = {}, accB0 = {}, accB1 = {};
  f32x16 lsvA = {}, lsvB = {};

  const int skey = tid >> 3, sdc = tid & 7;
  const int sdg = sdc ^ (skey & 7);
  const int skey2 = (tid + 256) >> 3;
  const int sdg2 = sdc ^ (skey2 & 7);

#define STAGE_K(bb_, k0_) do {                                                        \
    GLOAD_LDS16(Kg + tokBase + (size_t)((k0_) + skey) * 1024 + sdg * 8,               \
                (char*)Ks[bb_] + tid * 16);                                           \
    GLOAD_LDS16(Kg + tokBase + (size_t)((k0_) + skey2) * 1024 + sdg2 * 8,             \
                (char*)Ks[bb_] + (tid + 256) * 16);                                   \
  } while (0)

  STAGE_K(0, 0);
  for (int t = 0; t < 32; ++t) {
    const int bb = t & 1;
    const int k0 = t * 64;
    __syncthreads();                        // K stage(t) complete

    // V fragments for this tile: issue FIRST (latency hides under QK/softmax)
    bf16x8 bv0[4], bv1[4];
#pragma unroll
    for (int s = 0; s < 4; ++s) {
      bv0[s] = *(const bf16x8*)(Vp0 + k0 + s * 16);
      bv1[s] = *(const bf16x8*)(Vp1 + k0 + s * 16);
    }

    if (t < 31) STAGE_K(bb ^ 1, (t + 1) * 64);

    f32x16 svA0 = {}, svA1 = {}, svB0 = {}, svB1 = {};
    __builtin_amdgcn_s_setprio(1);
#pragma unroll
    for (int s = 0; s < 4; ++s) {
      bf16x8 kf0 = *(const bf16x8*)((const char*)Ks[bb] + lq * 128 +
                                    ((s * 32 + hi * 16) ^ ((lq & 7) << 4)));
      bf16x8 kf1 = *(const bf16x8*)((const char*)Ks[bb] + (32 + lq) * 128 +
                                    ((s * 32 + hi * 16) ^ ((lq & 7) << 4)));
      svA0 = __builtin_amdgcn_mfma_f32_32x32x16_bf16(kf0, qfA[s], svA0, 0, 0, 0);
      svB0 = __builtin_amdgcn_mfma_f32_32x32x16_bf16(kf0, qfB[s], svB0, 0, 0, 0);
      svA1 = __builtin_amdgcn_mfma_f32_32x32x16_bf16(kf1, qfA[s], svA1, 0, 0, 0);
      svB1 = __builtin_amdgcn_mfma_f32_32x32x16_bf16(kf1, qfB[s], svB1, 0, 0, 0);
    }
    __builtin_amdgcn_s_setprio(0);

#pragma unroll
    for (int i = 0; i < 16; ++i) svA0[i] = __builtin_amdgcn_exp2f(svA0[i]);
#pragma unroll
    for (int i = 0; i < 16; ++i) svA1[i] = __builtin_amdgcn_exp2f(svA1[i]);
#pragma unroll
    for (int i = 0; i < 16; ++i) svB0[i] = __builtin_amdgcn_exp2f(svB0[i]);
#pragma unroll
    for (int i = 0; i < 16; ++i) svB1[i] = __builtin_amdgcn_exp2f(svB1[i]);
    lsvA += svA0; lsvA += svA1;
    lsvB += svB0; lsvB += svB1;

    bf16x8 paA[4], paB[4];
#pragma unroll
    for (int kb = 0; kb < 2; ++kb) {
#pragma unroll
      for (int hh = 0; hh < 2; ++hh) {
        const int rb = hh * 8;
        {
          const f32x16& pv = kb ? svA1 : svA0;
          unsigned w01 = pkbf(pv[rb + 0], pv[rb + 1]);
          unsigned w23 = pkbf(pv[rb + 2], pv[rb + 3]);
          unsigned w45 = pkbf(pv[rb + 4], pv[rb + 5]);
          unsigned w67 = pkbf(pv[rb + 6], pv[rb + 7]);
          u32x2v ra = __builtin_amdgcn_permlane32_swap(w01, w45, false, false);
          u32x2v rc = __builtin_amdgcn_permlane32_swap(w23, w67, false, false);
          u32x4v fw = { ra[0], rc[0], ra[1], rc[1] };
          paA[kb * 2 + hh] = __builtin_bit_cast(bf16x8, fw);
        }
        {
          const f32x16& pv = kb ? svB1 : svB0;
          unsigned w01 = pkbf(pv[rb + 0], pv[rb + 1]);
          unsigned w23 = pkbf(pv[rb + 2], pv[rb + 3]);
          unsigned w45 = pkbf(pv[rb + 4], pv[rb + 5]);
          unsigned w67 = pkbf(pv[rb + 6], pv[rb + 7]);
          u32x2v ra = __builtin_amdgcn_permlane32_swap(w01, w45, false, false);
          u32x2v rc = __builtin_amdgcn_permlane32_swap(w23, w67, false, false);
          u32x4v fw = { ra[0], rc[0], ra[1], rc[1] };
          paB[kb * 2 + hh] = __builtin_bit_cast(bf16x8, fw);
        }
      }
    }

    __builtin_amdgcn_s_setprio(1);
#pragma unroll
    for (int s = 0; s < 4; ++s) {
      accA0 = __builtin_amdgcn_mfma_f32_32x32x16_bf16(paA[s], bv0[s], accA0, 0, 0, 0);
      accA1 = __builtin_amdgcn_mfma_f32_32x32x16_bf16(paA[s], bv1[s], accA1, 0, 0, 0);
      accB0 = __builtin_amdgcn_mfma_f32_32x32x16_bf16(paB[s], bv0[s], accB0, 0, 0, 0);
      accB1 = __builtin_amdgcn_mfma_f32_32x32x16_bf16(paB[s], bv1[s], accB1, 0, 0, 0);
    }
    __builtin_amdgcn_s_setprio(0);
  }
#undef STAGE_K

  float totA = 0.f, totB = 0.f;
#pragma unroll
  for (int i = 0; i < 16; ++i) { totA += lsvA[i]; totB += lsvB[i]; }
  totA += __shfl_xor(totA, 32);
  totB += __shfl_xor(totB, 32);
  const float invA = 1.0f / totA, invB = 1.0f / totB;
#pragma unroll
  for (int r = 0; r < 16; ++r) {
    const int q = (r & 3) + 8 * (r >> 2) + 4 * hi;
    const float ivA = __shfl(invA, q);
    const float ivB = __shfl(invB, q);
    const size_t rowA = (size_t)(b * 2048 + q0 + q) * 1024 + h * 64;
    const size_t rowB = (size_t)(b * 2048 + q0 + 32 + q) * 1024 + h * 64;
    O[rowA + lq]      = f2b(accA0[r] * ivA);
    O[rowA + 32 + lq] = f2b(accA1[r] * ivA);
    O[rowB + lq]      = f2b(accB0[r] * ivB);
    O[rowB + 32 + lq] = f2b(accB1[r] * ivB);
  }
}

// ---------------- launch ----------------
extern "C" void kernel_launch(void* const* d_in, const int* in_sizes, int n_in,
                              void* d_out, int out_size, void* d_ws, size_t ws_size,
                              hipStream_t stream) {
  const float* hs = (const float*)d_in[0];
  const float* wq = (const float*)d_in[2];
  const float* wk = (const float*)d_in[3];
  const float* wv = (const float*)d_in[4];
  const float* wo = (const float*)d_in[5];

  const size_t TOK = 8192, DD = 1024;
  u16* hsb  = (u16*)d_ws;                // [8192,1024]
  u16* wqkv = hsb + TOK * DD;            // [3072,1024]
  u16* wob  = wqkv + 3 * DD * DD;        // [1024,1024]
  u16* Qb   = wob + DD * DD;             // [8192,1024]
  u16* Kb   = Qb + TOK * DD;
  u16* Vtg  = Kb + TOK * DD;             // [64 bh][64 d][2048 s]
  u16* Cb   = Vtg + TOK * DD;            // ctx [8192,1024]

  cast_all_kernel<<<dim3(512, 5), 256, 0, stream>>>(hs, wq, wk, wv, wo, hsb, wqkv, wob);

  gemm_nt64<1><<<1536, 256, 0, stream>>>(hsb, wqkv, Qb, Kb, Vtg, 24);

  attn_fwd<<<dim3(512), 256, 0, stream>>>(Qb, Kb, Vtg, Cb);

  gemm_nt64<0><<<512, 256, 0, stream>>>(Cb, wob, d_out, nullptr, nullptr, 8);
}

// Round 15
// 189.235 us; speedup vs baseline: 1.2564x; 1.2564x over previous
//
#include <hip/hip_runtime.h>
#include <hip/hip_bf16.h>
#include <math.h>

typedef __bf16 bf16x8 __attribute__((ext_vector_type(8)));
typedef __bf16 bf16x2 __attribute__((ext_vector_type(2)));
typedef float f32x4 __attribute__((ext_vector_type(4)));
typedef float f32x16 __attribute__((ext_vector_type(16)));
typedef unsigned u32x2v __attribute__((ext_vector_type(2)));
typedef unsigned u32x4v __attribute__((ext_vector_type(4)));
typedef unsigned short u16;

#define QSCALE 0.04508422002778011f

__device__ __forceinline__ u16 f2b(float f) {
  union { float f; unsigned u; } x; x.f = f;
  unsigned r = x.u + 0x7fffu + ((x.u >> 16) & 1u);   // RNE to bf16
  return (u16)(r >> 16);
}

__device__ __forceinline__ unsigned pkbf(float a, float b) {
  bf16x2 t = { (__bf16)a, (__bf16)b };
  return __builtin_bit_cast(unsigned, t);
}

#define GLOAD_LDS16(g, s)                                                      \
  __builtin_amdgcn_global_load_lds(                                            \
      (__attribute__((address_space(1))) void*)(void*)(g),                     \
      (__attribute__((address_space(3))) void*)(s), 16, 0, 0)

// ---------------- all casts in one dispatch ----------------
__global__ void cast_all_kernel(const float* __restrict__ hs,
                                const float* __restrict__ wq, const float* __restrict__ wk,
                                const float* __restrict__ wv, const float* __restrict__ wo,
                                u16* __restrict__ hsb, u16* __restrict__ wqkv,
                                u16* __restrict__ wob) {
  const int w = blockIdx.y;
  const float* src; u16* dst; int n4; float scale = 1.0f;
  if (w == 0)      { src = hs; dst = hsb;                 n4 = 8192 * 1024 / 4; }
  else if (w == 1) { src = wq; dst = wqkv;                n4 = 1024 * 1024 / 4; scale = QSCALE; }
  else if (w == 2) { src = wk; dst = wqkv + 1024 * 1024;  n4 = 1024 * 1024 / 4; }
  else if (w == 3) { src = wv; dst = wqkv + 2 * 1024 * 1024; n4 = 1024 * 1024 / 4; }
  else             { src = wo; dst = wob;                 n4 = 1024 * 1024 / 4; }
  int i = blockIdx.x * blockDim.x + threadIdx.x;
  int stride = gridDim.x * blockDim.x;
  for (; i < n4; i += stride) {
    float4 v = ((const float4*)src)[i];
    ushort4 o;
    o.x = f2b(v.x * scale); o.y = f2b(v.y * scale);
    o.z = f2b(v.z * scale); o.w = f2b(v.w * scale);
    ((ushort4*)dst)[i] = o;
  }
}

// ------- 128x128 GEMM, BK=64 (R13-proven) + XCD-chunked 1D swizzle ---------
template <int OUT_MODE>   // 1: QKV region epilogue ; 0: fp32 out
__global__ __launch_bounds__(256) void gemm_nt64(const u16* __restrict__ A,
                                                 const u16* __restrict__ B,
                                                 void* __restrict__ O0,
                                                 u16* __restrict__ Ko,
                                                 u16* __restrict__ Vt,
                                                 int nbx) {
  __shared__ u16 As[128 * 64];
  __shared__ u16 Bs[128 * 64];
  const int tid = threadIdx.x;
  const int wid = tid >> 6, lane = tid & 63;
  const int fr = lane & 15, fg = lane >> 4;
  const int wr = wid >> 1, wc = wid & 1;
  const int id = blockIdx.x;
  const int cpx = gridDim.x >> 3;
  const int swzid = (id & 7) * cpx + (id >> 3);
  const int by = swzid / nbx, bx = swzid % nbx;
  const int m0 = by * 128, n0 = bx * 128;
  const int K = 1024;

  f32x4 acc[4][4] = {};

  for (int kt = 0; kt < K; kt += 64) {
#pragma unroll
    for (int i2 = 0; i2 < 4; ++i2) {
      int c = i2 * 256 + tid;
      int row = c >> 3, sl = c & 7;
      int kc = sl ^ (row & 7);                 // pre-swizzled source column
      GLOAD_LDS16(A + (size_t)(m0 + row) * K + kt + kc * 8, (char*)As + c * 16);
      GLOAD_LDS16(B + (size_t)(n0 + row) * K + kt + kc * 8, (char*)Bs + c * 16);
    }
    __syncthreads();

    bf16x8 af[4][2], bfr[4][2];
#pragma unroll
    for (int m = 0; m < 4; ++m) {
      const int row = wr * 64 + m * 16 + fr;
#pragma unroll
      for (int ks = 0; ks < 2; ++ks)
        af[m][ks] = *(const bf16x8*)((const char*)As + row * 128 +
                                     ((ks * 64 + fg * 16) ^ ((fr & 7) << 4)));
    }
#pragma unroll
    for (int n = 0; n < 4; ++n) {
      const int row = wc * 64 + n * 16 + fr;
#pragma unroll
      for (int ks = 0; ks < 2; ++ks)
        bfr[n][ks] = *(const bf16x8*)((const char*)Bs + row * 128 +
                                      ((ks * 64 + fg * 16) ^ ((fr & 7) << 4)));
    }
    __builtin_amdgcn_s_setprio(1);
#pragma unroll
    for (int m = 0; m < 4; ++m)
#pragma unroll
      for (int n = 0; n < 4; ++n)
#pragma unroll
        for (int ks = 0; ks < 2; ++ks)
          acc[m][n] = __builtin_amdgcn_mfma_f32_16x16x32_bf16(af[m][ks], bfr[n][ks],
                                                              acc[m][n], 0, 0, 0);
    __builtin_amdgcn_s_setprio(0);
    __syncthreads();
  }

#pragma unroll
  for (int m = 0; m < 4; ++m)
#pragma unroll
    for (int n = 0; n < 4; ++n) {
      int gr = m0 + wr * 64 + m * 16 + fg * 4;
      int gc = n0 + wc * 64 + n * 16 + fr;
      if (OUT_MODE == 0) {
#pragma unroll
        for (int j = 0; j < 4; ++j)
          ((float*)O0)[(size_t)(gr + j) * 1024 + gc] = acc[m][n][j];
      } else {
        const int region = n0 >> 10;   // 0=Q 1=K 2=V (block-uniform)
        if (region == 2) {
          int vc = gc - 2048;
          int hh = vc >> 6, dd = vc & 63, bb2 = gr >> 11, s0 = gr & 2047;
          ushort4 o;
          o.x = f2b(acc[m][n][0]); o.y = f2b(acc[m][n][1]);
          o.z = f2b(acc[m][n][2]); o.w = f2b(acc[m][n][3]);
          *(ushort4*)(Vt + (((size_t)bb2 * 16 + hh) * 64 + dd) * 2048 + s0) = o;
        } else {
          u16* dst = (region == 0) ? (u16*)O0 : Ko;
          int cc = gc & 1023;
#pragma unroll
          for (int j = 0; j < 4; ++j)
            dst[(size_t)(gr + j) * 1024 + cc] = f2b(acc[m][n][j]);
        }
      }
    }
}

// ---------------- fused flash attention (R4-proven, 86.4 us) ----------------
__global__ __launch_bounds__(256, 2) void attn_fwd(const u16* __restrict__ Q,
                                                   const u16* __restrict__ Kg,
                                                   const u16* __restrict__ Vtg,
                                                   u16* __restrict__ O) {
  __shared__ u16 Ks[2][64 * 64];
  __shared__ u16 Vs[2][64 * 64];
  const int tid = threadIdx.x;
  const int wid = tid >> 6, lane = tid & 63;
  const int lq = lane & 31, hi = lane >> 5;
  const int id = blockIdx.x;
  const int swz = (id & 7) * 64 + (id >> 3);
  const int qb = swz & 7, bh = swz >> 3;
  const int b = bh >> 4, h = bh & 15;
  const size_t tokBase = (size_t)b * 2048 * 1024 + h * 64;
  const size_t vBase = (size_t)bh * 64 * 2048;
  const int q0 = qb * 256 + wid * 64;

  bf16x8 qfA[4], qfB[4];
#pragma unroll
  for (int s = 0; s < 4; ++s) {
    qfA[s] = *(const bf16x8*)(Q + tokBase + (size_t)(q0 + lq) * 1024 + s * 16 + hi * 8);
    qfB[s] = *(const bf16x8*)(Q + tokBase + (size_t)(q0 + 32 + lq) * 1024 + s * 16 + hi * 8);
  }

  f32x16 accA0 = {}, accA1 = {}, accB0 = {}, accB1 = {};
  f32x16 lsvA = {}, lsvB = {};

  const int skey = tid >> 3, sdc = tid & 7;
  const int sdg = sdc ^ (skey & 7);
  const int skey2 = (tid + 256) >> 3;
  const int sdg2 = sdc ^ (skey2 & 7);

#define STAGE(bb_, k0_) do {                                                          \
    GLOAD_LDS16(Kg + tokBase + (size_t)((k0_) + skey) * 1024 + sdg * 8,               \
                (char*)Ks[bb_] + tid * 16);                                           \
    GLOAD_LDS16(Kg + tokBase + (size_t)((k0_) + skey2) * 1024 + sdg2 * 8,             \
                (char*)Ks[bb_] + (tid + 256) * 16);                                   \
    GLOAD_LDS16(Vtg + vBase + (size_t)skey * 2048 + (k0_) + sdg * 8,                  \
                (char*)Vs[bb_] + tid * 16);                                           \
    GLOAD_LDS16(Vtg + vBase + (size_t)skey2 * 2048 + (k0_) + sdg2 * 8,                \
                (char*)Vs[bb_] + (tid + 256) * 16);                                   \
  } while (0)

  STAGE(0, 0);
  for (int t = 0; t < 32; ++t) {
    const int bb = t & 1;
    __syncthreads();
    if (t < 31) STAGE(bb ^ 1, (t + 1) * 64);

    f32x16 svA0 = {}, svA1 = {}, svB0 = {}, svB1 = {};
    __builtin_amdgcn_s_setprio(1);
#pragma unroll
    for (int s = 0; s < 4; ++s) {
      bf16x8 kf0 = *(const bf16x8*)((const char*)Ks[bb] + lq * 128 +
                                    ((s * 32 + hi * 16) ^ ((lq & 7) << 4)));
      bf16x8 kf1 = *(const bf16x8*)((const char*)Ks[bb] + (32 + lq) * 128 +
                                    ((s * 32 + hi * 16) ^ ((lq & 7) << 4)));
      svA0 = __builtin_amdgcn_mfma_f32_32x32x16_bf16(kf0, qfA[s], svA0, 0, 0, 0);
      svB0 = __builtin_amdgcn_mfma_f32_32x32x16_bf16(kf0, qfB[s], svB0, 0, 0, 0);
      svA1 = __builtin_amdgcn_mfma_f32_32x32x16_bf16(kf1, qfA[s], svA1, 0, 0, 0);
      svB1 = __builtin_amdgcn_mfma_f32_32x32x16_bf16(kf1, qfB[s], svB1, 0, 0, 0);
    }
    __builtin_amdgcn_s_setprio(0);

#pragma unroll
    for (int i = 0; i < 16; ++i) svA0[i] = __builtin_amdgcn_exp2f(svA0[i]);
#pragma unroll
    for (int i = 0; i < 16; ++i) svA1[i] = __builtin_amdgcn_exp2f(svA1[i]);
#pragma unroll
    for (int i = 0; i < 16; ++i) svB0[i] = __builtin_amdgcn_exp2f(svB0[i]);
#pragma unroll
    for (int i = 0; i < 16; ++i) svB1[i] = __builtin_amdgcn_exp2f(svB1[i]);
    lsvA += svA0; lsvA += svA1;
    lsvB += svB0; lsvB += svB1;

    bf16x8 paA[4], paB[4];
#pragma unroll
    for (int kb = 0; kb < 2; ++kb) {
#pragma unroll
      for (int hh = 0; hh < 2; ++hh) {
        const int rb = hh * 8;
        {
          const f32x16& pv = kb ? svA1 : svA0;
          unsigned w01 = pkbf(pv[rb + 0], pv[rb + 1]);
          unsigned w23 = pkbf(pv[rb + 2], pv[rb + 3]);
          unsigned w45 = pkbf(pv[rb + 4], pv[rb + 5]);
          unsigned w67 = pkbf(pv[rb + 6], pv[rb + 7]);
          u32x2v ra = __builtin_amdgcn_permlane32_swap(w01, w45, false, false);
          u32x2v rc = __builtin_amdgcn_permlane32_swap(w23, w67, false, false);
          u32x4v fw = { ra[0], rc[0], ra[1], rc[1] };
          paA[kb * 2 + hh] = __builtin_bit_cast(bf16x8, fw);
        }
        {
          const f32x16& pv = kb ? svB1 : svB0;
          unsigned w01 = pkbf(pv[rb + 0], pv[rb + 1]);
          unsigned w23 = pkbf(pv[rb + 2], pv[rb + 3]);
          unsigned w45 = pkbf(pv[rb + 4], pv[rb + 5]);
          unsigned w67 = pkbf(pv[rb + 6], pv[rb + 7]);
          u32x2v ra = __builtin_amdgcn_permlane32_swap(w01, w45, false, false);
          u32x2v rc = __builtin_amdgcn_permlane32_swap(w23, w67, false, false);
          u32x4v fw = { ra[0], rc[0], ra[1], rc[1] };
          paB[kb * 2 + hh] = __builtin_bit_cast(bf16x8, fw);
        }
      }
    }

    __builtin_amdgcn_s_setprio(1);
#pragma unroll
    for (int s = 0; s < 4; ++s) {
      bf16x8 bv0 = *(const bf16x8*)((const char*)Vs[bb] + lq * 128 +
                                    ((s * 32 + hi * 16) ^ ((lq & 7) << 4)));
      bf16x8 bv1 = *(const bf16x8*)((const char*)Vs[bb] + (32 + lq) * 128 +
                                    ((s * 32 + hi * 16) ^ ((lq & 7) << 4)));
      accA0 = __builtin_amdgcn_mfma_f32_32x32x16_bf16(paA[s], bv0, accA0, 0, 0, 0);
      accA1 = __builtin_amdgcn_mfma_f32_32x32x16_bf16(paA[s], bv1, accA1, 0, 0, 0);
      accB0 = __builtin_amdgcn_mfma_f32_32x32x16_bf16(paB[s], bv0, accB0, 0, 0, 0);
      accB1 = __builtin_amdgcn_mfma_f32_32x32x16_bf16(paB[s], bv1, accB1, 0, 0, 0);
    }
    __builtin_amdgcn_s_setprio(0);
  }
#undef STAGE

  float totA = 0.f, totB = 0.f;
#pragma unroll
  for (int i = 0; i < 16; ++i) { totA += lsvA[i]; totB += lsvB[i]; }
  totA += __shfl_xor(totA, 32);
  totB += __shfl_xor(totB, 32);
  const float invA = 1.0f / totA, invB = 1.0f / totB;
#pragma unroll
  for (int r = 0; r < 16; ++r) {
    const int q = (r & 3) + 8 * (r >> 2) + 4 * hi;
    const float ivA = __shfl(invA, q);
    const float ivB = __shfl(invB, q);
    const size_t rowA = (size_t)(b * 2048 + q0 + q) * 1024 + h * 64;
    const size_t rowB = (size_t)(b * 2048 + q0 + 32 + q) * 1024 + h * 64;
    O[rowA + lq]      = f2b(accA0[r] * ivA);
    O[rowA + 32 + lq] = f2b(accA1[r] * ivA);
    O[rowB + lq]      = f2b(accB0[r] * ivB);
    O[rowB + 32 + lq] = f2b(accB1[r] * ivB);
  }
}

// ---------------- launch ----------------
extern "C" void kernel_launch(void* const* d_in, const int* in_sizes, int n_in,
                              void* d_out, int out_size, void* d_ws, size_t ws_size,
                              hipStream_t stream) {
  const float* hs = (const float*)d_in[0];
  const float* wq = (const float*)d_in[2];
  const float* wk = (const float*)d_in[3];
  const float* wv = (const float*)d_in[4];
  const float* wo = (const float*)d_in[5];

  const size_t TOK = 8192, DD = 1024;
  u16* hsb  = (u16*)d_ws;                // [8192,1024]
  u16* wqkv = hsb + TOK * DD;            // [3072,1024]
  u16* wob  = wqkv + 3 * DD * DD;        // [1024,1024]
  u16* Qb   = wob + DD * DD;             // [8192,1024]
  u16* Kb   = Qb + TOK * DD;
  u16* Vtg  = Kb + TOK * DD;             // [64 bh][64 d][2048 s]
  u16* Cb   = Vtg + TOK * DD;            // ctx [8192,1024]

  cast_all_kernel<<<dim3(512, 5), 256, 0, stream>>>(hs, wq, wk, wv, wo, hsb, wqkv, wob);

  gemm_nt64<1><<<1536, 256, 0, stream>>>(hsb, wqkv, Qb, Kb, Vtg, 24);

  attn_fwd<<<dim3(512), 256, 0, stream>>>(Qb, Kb, Vtg, Cb);

  gemm_nt64<0><<<512, 256, 0, stream>>>(Cb, wob, d_out, nullptr, nullptr, 8);
}